// Round 14
// baseline (58.223 us; speedup 1.0000x reference)
//
#include <hip/hip_runtime.h>
#include <hip/hip_bf16.h>
#include <math.h>

#define Bn 128
#define Tn 512
#define Cn 256
#define Hn 64
#define HP2 72          // padded bf16 LDS stride for attn tiles (144 B)
#define SCL 0.18033688011112042f   // log2(e)/8 : exp2-domain softmax scale

typedef __attribute__((ext_vector_type(8))) short short8v;   // 8 bf16
typedef __attribute__((ext_vector_type(4))) float float4v;   // MFMA C/D

__device__ __forceinline__ ushort f2bf(float f) {
    __hip_bfloat16 h = __float2bfloat16(f);   // RNE
    return *reinterpret_cast<ushort*>(&h);
}
__device__ __forceinline__ short8v pk8(float4 a, float4 b) {
    short8v r;
    r[0] = (short)f2bf(a.x); r[1] = (short)f2bf(a.y);
    r[2] = (short)f2bf(a.z); r[3] = (short)f2bf(a.w);
    r[4] = (short)f2bf(b.x); r[5] = (short)f2bf(b.y);
    r[6] = (short)f2bf(b.z); r[7] = (short)f2bf(b.w);
    return r;
}

// ---------------------------------------------------------------------------
// Prep: wcT2 = W columns regrouped for the nh-split kernel, bf16,
// PRE-SWIZZLED within each 512 B row (key = LDS row rr = row%96) so a linear
// global_load_lds lands XOR-swizzled (m173). Row order:
//   nh=0: [ q h0..63 | v h0..31 ]   nh=1: [ k h0..63 | v h32..63 ]
// ---------------------------------------------------------------------------
__global__ __launch_bounds__(256) void prep_w_kernel(
    const float* __restrict__ Wq, const float* __restrict__ Wk,
    const float* __restrict__ Wv, ushort* __restrict__ wcT2)
{
    const int row = blockIdx.x;          // 0..191
    const int c   = threadIdx.x;         // 0..255
    const int nh  = row / 96;
    const int rr  = row % 96;
    const int scol = (nh == 0) ? (rr < 64 ? rr : 128 + (rr - 64))
                               : (rr < 64 ? 64 + rr : 160 + (rr - 64));
    const float* W = (scol < 64) ? Wq : (scol < 128) ? Wk : Wv;
    const int h = scol & 63;
    wcT2[row * Cn + (c ^ ((rr & 7) << 3))] = f2bf(W[c * Hn + h]);
}

// ---------------------------------------------------------------------------
// QKV GEMM v9: x staging DELETED (it had zero cross-wave reuse — each wave
// only ever read its own strip back). A-fragments load DIRECTLY from global
// into registers (16 float4/thread, cvt in-reg), issued before the W DMA so
// both streams overlap; ONE barrier total. 2048 blocks x 256 thr (4 waves),
// 56 KB LDS -> 2 blocks/CU. Block = 64 rows x 96 cols (nh half, r13 decode:
// halves of a row-tile 8 apart -> same XCD -> x L2-hot). Epilogue = r13:
// v direct ushort4 (normal D = 4 consecutive t); q|k swapped D -> per-wave
// 2 KB XOR bounce (intra-wave, dedicated, no barrier) -> 2 full-line uint4.
// ---------------------------------------------------------------------------
__global__ __launch_bounds__(256) void qkv_mfma_kernel(
    const float* __restrict__ x, const ushort* __restrict__ wcT2,
    ushort* __restrict__ q, ushort* __restrict__ k, ushort* __restrict__ vT)
{
    __shared__ char lds[57344];
    // [0, 49152)     : W-half, 96 rows x 512 B, row-XOR-swizzled
    // [49152, 57344) : 4 x 2 KB per-wave q/k bounce
    const int BOFF = 49152;

    const int tid  = threadIdx.x;
    const int lane = tid & 63;
    const int wv   = tid >> 6;             // 0..3 : 16-row strip
    const int lr   = lane & 15;
    const int hi   = lane >> 4;

    const int bid     = blockIdx.x;
    const int nh      = (bid >> 3) & 1;                   // function half
    const int rowtile = (bid & 7) | ((bid >> 4) << 3);    // 0..1023
    const long rows0  = (long)rowtile * 64;

    // ---- x A-fragments: direct global loads (issued first, deepest) ----
    float4 xf[16];
    {
        const float4* xrow4 = (const float4*)(x + (rows0 + wv * 16 + lr) * Cn);
        #pragma unroll
        for (int ks = 0; ks < 8; ++ks) {
            xf[2 * ks]     = xrow4[ks * 8 + hi * 2];
            xf[2 * ks + 1] = xrow4[ks * 8 + hi * 2 + 1];
        }
    }

    // ---- W-half: 48 KB via global_load_lds, fire-and-forget ----
    {
        const char* gw = (const char*)wcT2 + (long)nh * 96 * 512;
        #pragma unroll
        for (int i = 0; i < 12; ++i) {
            int off = (wv * 12 + i) * 1024;
            __builtin_amdgcn_global_load_lds(
                (const __attribute__((address_space(1))) unsigned int*)(gw + off + (lane << 4)),
                (__attribute__((address_space(3))) unsigned int*)(lds + off),
                16, 0, 0);
        }
    }

    // ---- cvt x to bf16 fragments while the W DMA streams ----
    short8v a[8];
    #pragma unroll
    for (int ks = 0; ks < 8; ++ks)
        a[ks] = pk8(xf[2 * ks], xf[2 * ks + 1]);

    __syncthreads();   // drains W DMA; x already consumed into regs

    // ---- MFMA: per ks, 4 swapped (q|k) + 2 normal (v); W frags from LDS ----
    float4v aqk[4], av[2];
    #pragma unroll
    for (int j = 0; j < 4; ++j) aqk[j] = (float4v){0.f, 0.f, 0.f, 0.f};
    av[0] = (float4v){0.f, 0.f, 0.f, 0.f};
    av[1] = av[0];

    const int xxor = (lr & 7) << 4;
    #pragma unroll
    for (int ks = 0; ks < 8; ++ks) {
        const int kb = ks * 64 + hi * 16;
        #pragma unroll
        for (int j = 0; j < 4; ++j) {
            short8v wf = *(const short8v*)(lds + (j * 16 + lr) * 512 + (kb ^ xxor));
            aqk[j] = __builtin_amdgcn_mfma_f32_16x16x32_bf16(wf, a[ks], aqk[j], 0, 0, 0); // swapped
        }
        #pragma unroll
        for (int j = 0; j < 2; ++j) {
            short8v wf = *(const short8v*)(lds + (64 + j * 16 + lr) * 512 + (kb ^ xxor));
            av[j] = __builtin_amdgcn_mfma_f32_16x16x32_bf16(a[ks], wf, av[j], 0, 0, 0);   // normal
        }
    }

    // ---- v: direct ushort4 stores (D = 4 consecutive t at fixed h) ----
    {
        const int bb = (int)(rows0 >> 9);
        const int tl = (int)(rows0 & 511) + wv * 16 + hi * 4;
        #pragma unroll
        for (int j = 0; j < 2; ++j) {
            int h = nh * 32 + j * 16 + lr;
            ushort4 pk;
            pk.x = f2bf(av[j][0]); pk.y = f2bf(av[j][1]);
            pk.z = f2bf(av[j][2]); pk.w = f2bf(av[j][3]);
            *(ushort4*)(vT + ((long)bb * Hn + h) * Tn + tl) = pk;
        }
    }

    // ---- q|k: swapped D (4 consecutive h at fixed t) -> per-wave bounce ----
    {
        char* bnc = lds + BOFF + wv * 2048;    // [16 t][64 h] ushort, XOR-swz
        #pragma unroll
        for (int j = 0; j < 4; ++j) {
            ushort4 pk;
            pk.x = f2bf(aqk[j][0]); pk.y = f2bf(aqk[j][1]);
            pk.z = f2bf(aqk[j][2]); pk.w = f2bf(aqk[j][3]);
            *(ushort4*)(bnc + lr * 128 + ((j * 32 + hi * 8) ^ ((lr & 7) << 4))) = pk;
        }
        ushort* dst = nh ? k : q;
        #pragma unroll
        for (int i = 0; i < 2; ++i) {
            int t = i * 8 + (lane >> 3);
            int c = lane & 7;
            uint4 w = *(const uint4*)(bnc + t * 128 + ((c * 16) ^ ((t & 7) << 4)));
            *(uint4*)(dst + (rows0 + wv * 16 + t) * Hn + c * 8) = w;
        }
    }
}

// ---------------------------------------------------------------------------
// MFMA flash attention, 128-row Q tile, 8 waves (512 thr). Unchanged (r13).
// ---------------------------------------------------------------------------
__global__ __launch_bounds__(512) void attn_mfma_kernel(
    const ushort* __restrict__ q, const ushort* __restrict__ k,
    const ushort* __restrict__ vT, float* __restrict__ out)
{
    __shared__ ushort Ks[64 * HP2];        // [key s][h]
    __shared__ ushort Vt[64 * HP2];        // [h][key s]
    __shared__ ushort Pl[8][16 * HP2];     // per-wave P rows

    const int tid = threadIdx.x;
    const int f   = blockIdx.x;            // 0..511
    const int c   = f & 255;
    const int b   = c >> 1;
    const int par = c & 1;
    const int qtp = (f < 256) ? par : (3 - par);   // q-tile 0..3
    const int ntiles = 2 * qtp + 2;

    const long base  = (long)b * Tn * Hn;
    const int lane = tid & 63;
    const int wv   = tid >> 6;             // 0..7
    const int lr   = lane & 15;
    const int hi   = lane >> 4;

    const int qrow_g = qtp * 128 + wv * 16;
    const int mrow0  = qrow_g + hi * 4;

    short8v qa[2];
    {
        const ushort* qp = q + base + (long)(qrow_g + lr) * Hn + hi * 8;
        qa[0] = *(const short8v*)(qp);
        qa[1] = *(const short8v*)(qp + 32);
    }

    const int sr  = tid >> 3;
    const int sc8 = tid & 7;
    uint4 kreg = *(const uint4*)(k + base + (long)sr * Hn + sc8 * 8);
    uint4 vreg = *(const uint4*)(vT + base + (long)sr * Tn + sc8 * 8);

    float4v o[4];
    #pragma unroll
    for (int n = 0; n < 4; ++n) o[n] = (float4v){0.f, 0.f, 0.f, 0.f};
    float m[4], l[4];
    #pragma unroll
    for (int reg = 0; reg < 4; ++reg) { m[reg] = -INFINITY; l[reg] = 0.f; }

    for (int kt = 0; kt < ntiles; ++kt) {
        __syncthreads();
        *(uint4*)&Ks[sr * HP2 + sc8 * 8] = kreg;
        *(uint4*)&Vt[sr * HP2 + sc8 * 8] = vreg;
        __syncthreads();
        if (kt + 1 < ntiles) {
            kreg = *(const uint4*)(k  + base + (long)((kt + 1) * 64 + sr) * Hn + sc8 * 8);
            vreg = *(const uint4*)(vT + base + (long)sr * Tn + (kt + 1) * 64 + sc8 * 8);
        }
        if (kt * 64 > qrow_g + 15) continue;

        float4v s4[4];
        #pragma unroll
        for (int n = 0; n < 4; ++n) s4[n] = (float4v){0.f, 0.f, 0.f, 0.f};
        #pragma unroll
        for (int ks = 0; ks < 2; ++ks) {
            short8v a = qa[ks];
            #pragma unroll
            for (int n = 0; n < 4; ++n) {
                short8v bb = *(const short8v*)&Ks[(n * 16 + lr) * HP2 + ks * 32 + hi * 8];
                s4[n] = __builtin_amdgcn_mfma_f32_16x16x32_bf16(a, bb, s4[n], 0, 0, 0);
            }
        }

        const bool partial = (kt * 64 + 63 > qrow_g);
        if (partial) {
            #pragma unroll
            for (int n = 0; n < 4; ++n) {
                int kcol = kt * 64 + n * 16 + lr;
                #pragma unroll
                for (int reg = 0; reg < 4; ++reg) {
                    float y = s4[n][reg] * SCL;
                    s4[n][reg] = (kcol <= mrow0 + reg) ? y : -INFINITY;
                }
            }
        } else {
            #pragma unroll
            for (int n = 0; n < 4; ++n)
                #pragma unroll
                for (int reg = 0; reg < 4; ++reg) s4[n][reg] *= SCL;
        }

        #pragma unroll
        for (int reg = 0; reg < 4; ++reg) {
            float mx = fmaxf(fmaxf(s4[0][reg], s4[1][reg]),
                             fmaxf(s4[2][reg], s4[3][reg]));
            mx = fmaxf(mx, __shfl_xor(mx, 1));
            mx = fmaxf(mx, __shfl_xor(mx, 2));
            mx = fmaxf(mx, __shfl_xor(mx, 4));
            mx = fmaxf(mx, __shfl_xor(mx, 8));
            float mN = fmaxf(m[reg], mx);
            float sc = exp2f(m[reg] - mN);
            float ps = 0.f;
            #pragma unroll
            for (int n = 0; n < 4; ++n) {
                float p = exp2f(s4[n][reg] - mN);
                s4[n][reg] = p;
                ps += p;
            }
            ps += __shfl_xor(ps, 1);
            ps += __shfl_xor(ps, 2);
            ps += __shfl_xor(ps, 4);
            ps += __shfl_xor(ps, 8);
            l[reg] = l[reg] * sc + ps;
            m[reg] = mN;
            #pragma unroll
            for (int n = 0; n < 4; ++n) o[n][reg] *= sc;
        }

        #pragma unroll
        for (int n = 0; n < 4; ++n)
            #pragma unroll
            for (int reg = 0; reg < 4; ++reg)
                Pl[wv][(hi * 4 + reg) * HP2 + n * 16 + lr] = f2bf(s4[n][reg]);

        #pragma unroll
        for (int ks = 0; ks < 2; ++ks) {
            short8v a = *(const short8v*)&Pl[wv][lr * HP2 + ks * 32 + hi * 8];
            #pragma unroll
            for (int n = 0; n < 4; ++n) {
                short8v bb = *(const short8v*)&Vt[(n * 16 + lr) * HP2 + ks * 32 + hi * 8];
                o[n] = __builtin_amdgcn_mfma_f32_16x16x32_bf16(a, bb, o[n], 0, 0, 0);
            }
        }
    }

    #pragma unroll
    for (int reg = 0; reg < 4; ++reg) {
        float inv = 1.0f / l[reg];
        float* orow = out + base + (long)(mrow0 + reg) * Hn;
        #pragma unroll
        for (int n = 0; n < 4; ++n)
            orow[n * 16 + lr] = o[n][reg] * inv;
    }
}

extern "C" void kernel_launch(void* const* d_in, const int* in_sizes, int n_in,
                              void* d_out, int out_size, void* d_ws, size_t ws_size,
                              hipStream_t stream) {
    const float* x  = (const float*)d_in[0];
    const float* Wq = (const float*)d_in[1];
    const float* Wk = (const float*)d_in[2];
    const float* Wv = (const float*)d_in[3];
    float* out = (float*)d_out;

    const size_t n = (size_t)Bn * Tn * Hn;
    ushort* qws  = (ushort*)d_ws;
    ushort* kws  = qws + n;
    ushort* vTs  = kws + n;
    ushort* wcT2 = vTs + n;      // regrouped pre-swizzled bf16 W, 96 KB

    prep_w_kernel<<<dim3(192), 256, 0, stream>>>(Wq, Wk, Wv, wcT2);
    qkv_mfma_kernel<<<dim3(2048), 256, 0, stream>>>(x, wcT2, qws, kws, vTs);
    attn_mfma_kernel<<<dim3(512), 512, 0, stream>>>(qws, kws, vTs, out);
}

// Round 15
// 48.679 us; speedup vs baseline: 1.1961x; 1.1961x over previous
//
#include <hip/hip_runtime.h>
#include <hip/hip_bf16.h>
#include <math.h>

#define Bn 128
#define Tn 512
#define Cn 256
#define Hn 64
#define HP2 72          // padded bf16 LDS stride for attn tiles (144 B)
#define SCL 0.18033688011112042f   // log2(e)/8 : exp2-domain softmax scale

typedef __attribute__((ext_vector_type(8))) short short8v;   // 8 bf16
typedef __attribute__((ext_vector_type(4))) float float4v;   // MFMA C/D

__device__ __forceinline__ ushort f2bf(float f) {
    __hip_bfloat16 h = __float2bfloat16(f);   // RNE
    return *reinterpret_cast<ushort*>(&h);
}

// ---------------------------------------------------------------------------
// Prep: wcT3 = W as 4 contiguous K-chunks of [192 out-cols][64 k] bf16,
// pre-swizzled (k2 ^ ((row&7)<<3) in ushorts == byte ^ ((row&7)<<4)) so a
// LINEAR global_load_lds of a 24 KB chunk lands XOR-swizzled in LDS.
// Row order = output col: 0-63 q, 64-127 k, 128-191 v.
// ---------------------------------------------------------------------------
__global__ __launch_bounds__(256) void prep_w_kernel(
    const float* __restrict__ Wq, const float* __restrict__ Wk,
    const float* __restrict__ Wv, ushort* __restrict__ wcT3)
{
    const int row = blockIdx.x;          // 0..191 : output col
    const int c   = threadIdx.x;         // 0..255 : k
    const int kc  = c >> 6;
    const int k2  = c & 63;
    const float* W = (row < 64) ? Wq : (row < 128) ? Wk : Wv;
    const int h = row & 63;
    wcT3[(kc * 192 + row) * 64 + (k2 ^ ((row & 7) << 3))] = f2bf(W[c * Hn + h]);
}

// ---------------------------------------------------------------------------
// QKV GEMM v10 (m97-shaped): 512 blocks x 256 thr (4 waves), block tile
// 128 rows x 192 cols (FULL N -> x read once), K chunked BK=64, LDS
// double-buffered 2x(16K x + 24K W) = 80 KB -> 2 blocks/CU.
// Wave grid 2x2: wave-tile 64 rows x 96 cols (R=4 strips, F=6 frags):
// per ks 10 ds_read_b128 feed 24 MFMAs (2.8x better FLOP/LDS-byte than r13).
// Pipeline: per chunk {barrier; issue W-DMA + x loads for c+1; MFMA on c;
// cvt+ds_write c+1} — HBM latency hides under compute. Epilogue: q/k/v all
// bounced via freed LDS buffers -> 12 coalesced uint4 stores/thread.
// ---------------------------------------------------------------------------
__global__ __launch_bounds__(256) void qkv_mfma_kernel(
    const float* __restrict__ x, const ushort* __restrict__ wcT3,
    ushort* __restrict__ q, ushort* __restrict__ k, ushort* __restrict__ vT)
{
    __shared__ char lds[81920];
    // xbuf0 @ 0, xbuf1 @ 16384 (each [128 r][64 k] bf16, 128 B rows, swz)
    // wbuf0 @ 32768, wbuf1 @ 57344 (each [192 r][64 k] bf16, swz)
    // epilogue overlay: q-bounce @ 0 (16K), k-bounce @ 16384 (16K),
    //                   v-bounce @ 32768 (16K, [64 h][128 t])

    const int tid  = threadIdx.x;
    const int lane = tid & 63;
    const int wv   = tid >> 6;             // 0..3
    const int lr   = lane & 15;
    const int hi   = lane >> 4;
    const int wr   = wv >> 1;              // 0..1 : 64-row group
    const int wc   = wv & 1;               // 0..1 : 96-col group
    const long rows0 = (long)blockIdx.x * 128;

    // ---- prologue: W chunk0 DMA + x chunk0 ----
    {
        const char* gw = (const char*)wcT3;
        #pragma unroll
        for (int i = 0; i < 6; ++i) {
            int off = (wv * 6 + i) * 1024;
            __builtin_amdgcn_global_load_lds(
                (const __attribute__((address_space(1))) unsigned int*)(gw + off + (lane << 4)),
                (__attribute__((address_space(3))) unsigned int*)(lds + 32768 + off),
                16, 0, 0);
        }
    }
    {
        const float4* x4 = (const float4*)x;
        float4 xr[8];
        #pragma unroll
        for (int i = 0; i < 8; ++i) {
            int idx = tid + i * 256;                 // 0..2047
            int r   = idx >> 4;
            int f   = idx & 15;
            xr[i] = x4[(rows0 + r) * 64 + f];        // chunk 0: f4 0..15
        }
        #pragma unroll
        for (int i = 0; i < 8; ++i) {
            int idx = tid + i * 256;
            int r   = idx >> 4;
            int f   = idx & 15;
            union { ushort u[4]; uint2 p; } pk;
            pk.u[0] = f2bf(xr[i].x); pk.u[1] = f2bf(xr[i].y);
            pk.u[2] = f2bf(xr[i].z); pk.u[3] = f2bf(xr[i].w);
            *(uint2*)(lds + r * 128 + ((f * 8) ^ ((r & 7) << 4))) = pk.p;
        }
    }

    float4v acc[4][6];
    #pragma unroll
    for (int s = 0; s < 4; ++s)
        #pragma unroll
        for (int n = 0; n < 6; ++n) acc[s][n] = (float4v){0.f, 0.f, 0.f, 0.f};

    for (int c = 0; c < 4; ++c) {
        __syncthreads();     // buf[c&1] staged (DMA drained by barrier's vmcnt)

        const int par = c & 1;
        float4 xn[8];
        if (c < 3) {
            // issue next W chunk DMA -> wbuf[!par]
            const char* gw = (const char*)wcT3 + (long)(c + 1) * 24576;
            #pragma unroll
            for (int i = 0; i < 6; ++i) {
                int off = (wv * 6 + i) * 1024;
                __builtin_amdgcn_global_load_lds(
                    (const __attribute__((address_space(1))) unsigned int*)(gw + off + (lane << 4)),
                    (__attribute__((address_space(3))) unsigned int*)(lds + 32768 + (1 - par) * 24576 + off),
                    16, 0, 0);
            }
            // issue next x loads
            const float4* x4 = (const float4*)x;
            #pragma unroll
            for (int i = 0; i < 8; ++i) {
                int idx = tid + i * 256;
                int r   = idx >> 4;
                int f   = idx & 15;
                xn[i] = x4[(rows0 + r) * 64 + (c + 1) * 16 + f];
            }
        }

        // ---- MFMA on chunk c ----
        const char* xb = lds + par * 16384;
        const char* wb = lds + 32768 + par * 24576;
        #pragma unroll
        for (int ks = 0; ks < 2; ++ks) {
            const int kb = ks * 64 + hi * 16;
            short8v a[4];
            #pragma unroll
            for (int s = 0; s < 4; ++s) {
                int r = wr * 64 + s * 16 + lr;
                a[s] = *(const short8v*)(xb + r * 128 + (kb ^ ((r & 7) << 4)));
            }
            #pragma unroll
            for (int n = 0; n < 6; ++n) {
                int wrow = wc * 96 + n * 16 + lr;
                short8v wf = *(const short8v*)(wb + wrow * 128 + (kb ^ ((wrow & 7) << 4)));
                #pragma unroll
                for (int s = 0; s < 4; ++s)
                    acc[s][n] = __builtin_amdgcn_mfma_f32_16x16x32_bf16(a[s], wf, acc[s][n], 0, 0, 0);
            }
        }

        // ---- cvt + ds_write next x chunk -> xbuf[!par] ----
        if (c < 3) {
            char* xd = lds + (1 - par) * 16384;
            #pragma unroll
            for (int i = 0; i < 8; ++i) {
                int idx = tid + i * 256;
                int r   = idx >> 4;
                int f   = idx & 15;
                union { ushort u[4]; uint2 p; } pk;
                pk.u[0] = f2bf(xn[i].x); pk.u[1] = f2bf(xn[i].y);
                pk.u[2] = f2bf(xn[i].z); pk.u[3] = f2bf(xn[i].w);
                *(uint2*)(xd + r * 128 + ((f * 8) ^ ((r & 7) << 4))) = pk.p;
            }
        }
    }

    __syncthreads();   // all MFMA reads done -> overlay buffers as bounce

    // ---- bounce writes: D lane (lr,hi) holds h = col16+lr, t = tb+reg ----
    #pragma unroll
    for (int s = 0; s < 4; ++s) {
        const int tb = wr * 64 + s * 16 + hi * 4;      // local t (+reg)
        #pragma unroll
        for (int n = 0; n < 6; ++n) {
            const int col16 = wc * 96 + n * 16;        // wave-uniform
            if (col16 < 128) {                         // q or k: [t][h] 2B
                char* qkb = lds + ((col16 < 64) ? 0 : 16384);
                int h = (col16 + lr) & 63;
                #pragma unroll
                for (int reg = 0; reg < 4; ++reg) {
                    int t = tb + reg;
                    *(ushort*)(qkb + t * 128 + ((h * 2) ^ ((t & 7) << 4))) =
                        f2bf(acc[s][n][reg]);
                }
            } else {                                   // v: [h][t] ushort4
                int h = col16 - 128 + lr;
                ushort4 pk;
                pk.x = f2bf(acc[s][n][0]); pk.y = f2bf(acc[s][n][1]);
                pk.z = f2bf(acc[s][n][2]); pk.w = f2bf(acc[s][n][3]);
                *(ushort4*)(lds + 32768 + h * 256 + ((tb * 2) ^ ((h & 7) << 4))) = pk;
            }
        }
    }
    __syncthreads();

    // ---- coalesced stores: 4 uint4/thread each for q, k, vT ----
    {
        const int bb = (int)(rows0 >> 9);
        const int t0 = (int)(rows0 & 511);
        #pragma unroll
        for (int i = 0; i < 4; ++i) {
            int idx = tid + i * 256;                   // 0..1023
            int t   = idx >> 3;
            int f   = idx & 7;
            uint4 vq = *(const uint4*)(lds + t * 128 + ((f * 16) ^ ((t & 7) << 4)));
            *(uint4*)(q + (rows0 + t) * Hn + f * 8) = vq;
            uint4 vk = *(const uint4*)(lds + 16384 + t * 128 + ((f * 16) ^ ((t & 7) << 4)));
            *(uint4*)(k + (rows0 + t) * Hn + f * 8) = vk;
            int h  = idx >> 4;
            int fv = idx & 15;
            uint4 vv = *(const uint4*)(lds + 32768 + h * 256 + ((fv * 16) ^ ((h & 7) << 4)));
            *(uint4*)(vT + ((long)bb * Hn + h) * Tn + t0 + fv * 8) = vv;
        }
    }
}

// ---------------------------------------------------------------------------
// MFMA flash attention, 128-row Q tile, 8 waves (512 thr). Unchanged (r13).
// ---------------------------------------------------------------------------
__global__ __launch_bounds__(512) void attn_mfma_kernel(
    const ushort* __restrict__ q, const ushort* __restrict__ k,
    const ushort* __restrict__ vT, float* __restrict__ out)
{
    __shared__ ushort Ks[64 * HP2];        // [key s][h]
    __shared__ ushort Vt[64 * HP2];        // [h][key s]
    __shared__ ushort Pl[8][16 * HP2];     // per-wave P rows

    const int tid = threadIdx.x;
    const int f   = blockIdx.x;            // 0..511
    const int c   = f & 255;
    const int b   = c >> 1;
    const int par = c & 1;
    const int qtp = (f < 256) ? par : (3 - par);   // q-tile 0..3
    const int ntiles = 2 * qtp + 2;

    const long base  = (long)b * Tn * Hn;
    const int lane = tid & 63;
    const int wv   = tid >> 6;             // 0..7
    const int lr   = lane & 15;
    const int hi   = lane >> 4;

    const int qrow_g = qtp * 128 + wv * 16;
    const int mrow0  = qrow_g + hi * 4;

    short8v qa[2];
    {
        const ushort* qp = q + base + (long)(qrow_g + lr) * Hn + hi * 8;
        qa[0] = *(const short8v*)(qp);
        qa[1] = *(const short8v*)(qp + 32);
    }

    const int sr  = tid >> 3;
    const int sc8 = tid & 7;
    uint4 kreg = *(const uint4*)(k + base + (long)sr * Hn + sc8 * 8);
    uint4 vreg = *(const uint4*)(vT + base + (long)sr * Tn + sc8 * 8);

    float4v o[4];
    #pragma unroll
    for (int n = 0; n < 4; ++n) o[n] = (float4v){0.f, 0.f, 0.f, 0.f};
    float m[4], l[4];
    #pragma unroll
    for (int reg = 0; reg < 4; ++reg) { m[reg] = -INFINITY; l[reg] = 0.f; }

    for (int kt = 0; kt < ntiles; ++kt) {
        __syncthreads();
        *(uint4*)&Ks[sr * HP2 + sc8 * 8] = kreg;
        *(uint4*)&Vt[sr * HP2 + sc8 * 8] = vreg;
        __syncthreads();
        if (kt + 1 < ntiles) {
            kreg = *(const uint4*)(k  + base + (long)((kt + 1) * 64 + sr) * Hn + sc8 * 8);
            vreg = *(const uint4*)(vT + base + (long)sr * Tn + (kt + 1) * 64 + sc8 * 8);
        }
        if (kt * 64 > qrow_g + 15) continue;

        float4v s4[4];
        #pragma unroll
        for (int n = 0; n < 4; ++n) s4[n] = (float4v){0.f, 0.f, 0.f, 0.f};
        #pragma unroll
        for (int ks = 0; ks < 2; ++ks) {
            short8v a = qa[ks];
            #pragma unroll
            for (int n = 0; n < 4; ++n) {
                short8v bb = *(const short8v*)&Ks[(n * 16 + lr) * HP2 + ks * 32 + hi * 8];
                s4[n] = __builtin_amdgcn_mfma_f32_16x16x32_bf16(a, bb, s4[n], 0, 0, 0);
            }
        }

        const bool partial = (kt * 64 + 63 > qrow_g);
        if (partial) {
            #pragma unroll
            for (int n = 0; n < 4; ++n) {
                int kcol = kt * 64 + n * 16 + lr;
                #pragma unroll
                for (int reg = 0; reg < 4; ++reg) {
                    float y = s4[n][reg] * SCL;
                    s4[n][reg] = (kcol <= mrow0 + reg) ? y : -INFINITY;
                }
            }
        } else {
            #pragma unroll
            for (int n = 0; n < 4; ++n)
                #pragma unroll
                for (int reg = 0; reg < 4; ++reg) s4[n][reg] *= SCL;
        }

        #pragma unroll
        for (int reg = 0; reg < 4; ++reg) {
            float mx = fmaxf(fmaxf(s4[0][reg], s4[1][reg]),
                             fmaxf(s4[2][reg], s4[3][reg]));
            mx = fmaxf(mx, __shfl_xor(mx, 1));
            mx = fmaxf(mx, __shfl_xor(mx, 2));
            mx = fmaxf(mx, __shfl_xor(mx, 4));
            mx = fmaxf(mx, __shfl_xor(mx, 8));
            float mN = fmaxf(m[reg], mx);
            float sc = exp2f(m[reg] - mN);
            float ps = 0.f;
            #pragma unroll
            for (int n = 0; n < 4; ++n) {
                float p = exp2f(s4[n][reg] - mN);
                s4[n][reg] = p;
                ps += p;
            }
            ps += __shfl_xor(ps, 1);
            ps += __shfl_xor(ps, 2);
            ps += __shfl_xor(ps, 4);
            ps += __shfl_xor(ps, 8);
            l[reg] = l[reg] * sc + ps;
            m[reg] = mN;
            #pragma unroll
            for (int n = 0; n < 4; ++n) o[n][reg] *= sc;
        }

        #pragma unroll
        for (int n = 0; n < 4; ++n)
            #pragma unroll
            for (int reg = 0; reg < 4; ++reg)
                Pl[wv][(hi * 4 + reg) * HP2 + n * 16 + lr] = f2bf(s4[n][reg]);

        #pragma unroll
        for (int ks = 0; ks < 2; ++ks) {
            short8v a = *(const short8v*)&Pl[wv][lr * HP2 + ks * 32 + hi * 8];
            #pragma unroll
            for (int n = 0; n < 4; ++n) {
                short8v bb = *(const short8v*)&Vt[(n * 16 + lr) * HP2 + ks * 32 + hi * 8];
                o[n] = __builtin_amdgcn_mfma_f32_16x16x32_bf16(a, bb, o[n], 0, 0, 0);
            }
        }
    }

    #pragma unroll
    for (int reg = 0; reg < 4; ++reg) {
        float inv = 1.0f / l[reg];
        float* orow = out + base + (long)(mrow0 + reg) * Hn;
        #pragma unroll
        for (int n = 0; n < 4; ++n)
            orow[n * 16 + lr] = o[n][reg] * inv;
    }
}

extern "C" void kernel_launch(void* const* d_in, const int* in_sizes, int n_in,
                              void* d_out, int out_size, void* d_ws, size_t ws_size,
                              hipStream_t stream) {
    const float* x  = (const float*)d_in[0];
    const float* Wq = (const float*)d_in[1];
    const float* Wk = (const float*)d_in[2];
    const float* Wv = (const float*)d_in[3];
    float* out = (float*)d_out;

    const size_t n = (size_t)Bn * Tn * Hn;
    ushort* qws  = (ushort*)d_ws;
    ushort* kws  = qws + n;
    ushort* vTs  = kws + n;
    ushort* wcT3 = vTs + n;      // K-chunked pre-swizzled bf16 W, 96 KB

    prep_w_kernel<<<dim3(192), 256, 0, stream>>>(Wq, Wk, Wv, wcT3);
    qkv_mfma_kernel<<<dim3(512), 256, 0, stream>>>(x, wcT3, qws, kws, vTs);
    attn_mfma_kernel<<<dim3(512), 512, 0, stream>>>(qws, kws, vTs, out);
}